// Round 1
// baseline (564.461 us; speedup 1.0000x reference)
//
#include <hip/hip_runtime.h>
#include <hip/hip_bf16.h>

#define NPIX 4096
#define CCH  256
#define HID  64
#define BAT  4

using f32x4 = __attribute__((ext_vector_type(4))) float;
using s16x8 = __attribute__((ext_vector_type(8))) short;
using u16x4 = __attribute__((ext_vector_type(4))) unsigned short;

__device__ __forceinline__ unsigned short f2bf(float f) {
    __hip_bfloat16 h = __float2bfloat16(f);
    return __builtin_bit_cast(unsigned short, h);
}
__device__ __forceinline__ float bf2f(unsigned short u) {
    unsigned int v = ((unsigned int)u) << 16;
    return __builtin_bit_cast(float, v);
}
__device__ __forceinline__ s16x8 ldg_frag(const unsigned short* p) {
    uint4 v = *reinterpret_cast<const uint4*>(p);
    return __builtin_bit_cast(s16x8, v);
}
__device__ __forceinline__ s16x8 lds_frag(const unsigned short* p) {
    return *reinterpret_cast<const s16x8*>(p);
}

// ---------------------------------------------------------------------------
// Projection kernel: for s in {0,1}, b in {0..3}:
//   q = Wq x + bq, k = Wk x + bk  -> stored [n][h] as bf16 hi/lo pairs
//   v = Wv x + bv                 -> stored [c][m] bf16 (natural layout)
// fp32 VALU compute; x tile staged in LDS; W rows via wave-uniform s_loads.
// ---------------------------------------------------------------------------
__global__ __launch_bounds__(256, 2) void proj_kernel(
    const float* __restrict__ x1, const float* __restrict__ x2,
    const float* __restrict__ Wq, const float* __restrict__ bq,
    const float* __restrict__ Wk, const float* __restrict__ bk,
    const float* __restrict__ Wv, const float* __restrict__ bv,
    unsigned short* __restrict__ Qh, unsigned short* __restrict__ Ql,
    unsigned short* __restrict__ Kh, unsigned short* __restrict__ Kl,
    unsigned short* __restrict__ Vt)
{
    __shared__ float xs[CCH][64];   // 64 KB, bank-conflict-free (2-way only)

    const int Lb = blockIdx.x;
    const int sb = Lb & 7;          // XCD-locality swizzle
    const int ntile = Lb >> 3;
    const int s = sb >> 2, b = sb & 3;
    const float* x = s ? x2 : x1;
    const int n0 = ntile * 64;
    const int t = threadIdx.x;
    const int n = t & 63;
    const int w = __builtin_amdgcn_readfirstlane(t >> 6);  // wave id, uniform

    // stage x[b][0:256][n0:n0+64] into LDS (coalesced)
    const float* xb = x + (size_t)(b * CCH) * NPIX + n0;
    #pragma unroll 4
    for (int i = 0; i < 64; ++i) {
        int c = i * 4 + (t >> 6);
        xs[c][n] = xb[(size_t)c * NPIX + n];
    }
    __syncthreads();

    const int sbN = (s * BAT + b) * NPIX;   // row base for Q/K outputs
    const int sbC = (s * BAT + b) * CCH;    // row base for Vt outputs

    // each wave owns 96 output rows (h), processed in 6 chunks of 16
    for (int chunk = 0; chunk < 6; ++chunk) {
        int h0 = w * 96 + chunk * 16;       // wave-uniform
        const float* W; const float* bias; int hh; int kind;
        if (h0 < 64)       { W = Wq; bias = bq; hh = h0;       kind = 0; }
        else if (h0 < 128) { W = Wk; bias = bk; hh = h0 - 64;  kind = 1; }
        else               { W = Wv; bias = bv; hh = h0 - 128; kind = 2; }

        float acc[16];
        #pragma unroll
        for (int j = 0; j < 16; ++j) acc[j] = 0.f;

        const float* Wr = W + hh * CCH;
        #pragma unroll 4
        for (int c = 0; c < CCH; ++c) {
            float xv = xs[c][n];
            #pragma unroll
            for (int j = 0; j < 16; ++j)
                acc[j] = fmaf(Wr[j * CCH + c], xv, acc[j]);
        }

        if (kind < 2) {
            // split each fp32 value into bf16 hi + residual lo, store [n][h]
            unsigned short* dh = (kind == 0 ? Qh : Kh) + (size_t)(sbN + n0 + n) * HID + hh;
            unsigned short* dl = (kind == 0 ? Ql : Kl) + (size_t)(sbN + n0 + n) * HID + hh;
            #pragma unroll
            for (int half = 0; half < 2; ++half) {
                s16x8 hv, lv;
                #pragma unroll
                for (int j = 0; j < 8; ++j) {
                    float v = acc[half * 8 + j] + bias[hh + half * 8 + j];
                    unsigned short hb = f2bf(v);
                    float res = v - bf2f(hb);
                    hv[j] = (short)hb;
                    lv[j] = (short)f2bf(res);
                }
                *reinterpret_cast<s16x8*>(dh + half * 8) = hv;
                *reinterpret_cast<s16x8*>(dl + half * 8) = lv;
            }
        } else {
            // V: natural [c][m] layout, coalesced 2B stores
            #pragma unroll
            for (int j = 0; j < 16; ++j) {
                float v = acc[j] + bias[hh + j];
                Vt[(size_t)(sbC + hh + j) * NPIX + n0 + n] = f2bf(v);
            }
        }
    }
}

// ---------------------------------------------------------------------------
// Flash cross-attention, transposed orientation:
//   S^T = K Q^T (split-bf16, 3 MFMA), online softmax over m (cross-wave via
//   LDS partials), O^T = V^T P^T. K/V fragments load straight from global.
// Block: 64 query rows (n), 4 waves; wave owns 16 m-rows (QK) / 64 c-rows (PV).
// ---------------------------------------------------------------------------
__global__ __launch_bounds__(256, 2) void attn_kernel(
    const float* __restrict__ x1, const float* __restrict__ x2,
    const unsigned short* __restrict__ Qh, const unsigned short* __restrict__ Ql,
    const unsigned short* __restrict__ Kh, const unsigned short* __restrict__ Kl,
    const unsigned short* __restrict__ Vt,
    const float* __restrict__ gamma,
    float* __restrict__ out)
{
    __shared__ unsigned short PT[64 * 72];   // P^T [n][m], +8 pad
    __shared__ float pmax[4][64];
    __shared__ float psum[4][64];

    const int Lb = blockIdx.x;
    const int g = Lb & 7;                    // XCD-locality swizzle
    const int ntile = Lb >> 3;
    const int d = g >> 2, b = g & 3;
    const int s = d, r = 1 - d;
    const int n0 = ntile * 64;

    const int t = threadIdx.x;
    const int lane = t & 63;
    const int w = __builtin_amdgcn_readfirstlane(t >> 6);
    const int quad = lane >> 4, lq = lane & 15;

    const unsigned short* Qhb = Qh + (size_t)(s * BAT + b) * NPIX * HID;
    const unsigned short* Qlb = Ql + (size_t)(s * BAT + b) * NPIX * HID;
    const unsigned short* Khb = Kh + (size_t)(r * BAT + b) * NPIX * HID;
    const unsigned short* Klb = Kl + (size_t)(r * BAT + b) * NPIX * HID;
    const unsigned short* Vb  = Vt + (size_t)(r * BAT + b) * CCH * NPIX;

    // Q B-fragments, persistent in registers (hi+lo): 4 ntiles x 2 ksteps
    s16x8 qhf[4][2], qlf[4][2];
    #pragma unroll
    for (int nt = 0; nt < 4; ++nt)
        #pragma unroll
        for (int ks = 0; ks < 2; ++ks) {
            int off = (n0 + nt * 16 + lq) * HID + ks * 32 + quad * 8;
            qhf[nt][ks] = ldg_frag(Qhb + off);
            qlf[nt][ks] = ldg_frag(Qlb + off);
        }

    f32x4 Oacc[4][4];
    #pragma unroll
    for (int rt = 0; rt < 4; ++rt)
        #pragma unroll
        for (int ct = 0; ct < 4; ++ct)
            Oacc[rt][ct] = (f32x4){0.f, 0.f, 0.f, 0.f};

    float Mi[4], Li[4];
    #pragma unroll
    for (int nt = 0; nt < 4; ++nt) { Mi[nt] = -3.0e38f; Li[nt] = 0.f; }

    // preload K/V fragments for iter 0
    s16x8 khf[2], klf[2], vf[4][2];
    {
        int ko = (w * 16 + lq) * HID + quad * 8;
        khf[0] = ldg_frag(Khb + ko);      khf[1] = ldg_frag(Khb + ko + 32);
        klf[0] = ldg_frag(Klb + ko);      klf[1] = ldg_frag(Klb + ko + 32);
        #pragma unroll
        for (int rt = 0; rt < 4; ++rt)
            #pragma unroll
            for (int ks = 0; ks < 2; ++ks)
                vf[rt][ks] = ldg_frag(Vb + (size_t)(w * 64 + rt * 16 + lq) * NPIX
                                         + ks * 32 + quad * 8);
    }

    for (int it = 0; it < 64; ++it) {
        // ---- S^T = K Q^T (this wave's 16 m-rows x 64 n-cols) ----
        f32x4 Sacc[4];
        #pragma unroll
        for (int nt = 0; nt < 4; ++nt) Sacc[nt] = (f32x4){0.f, 0.f, 0.f, 0.f};
        #pragma unroll
        for (int ks = 0; ks < 2; ++ks)
            #pragma unroll
            for (int nt = 0; nt < 4; ++nt) {
                Sacc[nt] = __builtin_amdgcn_mfma_f32_16x16x32_bf16(khf[ks], qhf[nt][ks], Sacc[nt], 0, 0, 0);
                Sacc[nt] = __builtin_amdgcn_mfma_f32_16x16x32_bf16(khf[ks], qlf[nt][ks], Sacc[nt], 0, 0, 0);
                Sacc[nt] = __builtin_amdgcn_mfma_f32_16x16x32_bf16(klf[ks], qhf[nt][ks], Sacc[nt], 0, 0, 0);
            }

        const int it2 = (it < 63) ? it + 1 : 63;
        // prefetch next K fragments (regs free after MFMA issue)
        {
            int ko = (it2 * 64 + w * 16 + lq) * HID + quad * 8;
            khf[0] = ldg_frag(Khb + ko);  khf[1] = ldg_frag(Khb + ko + 32);
            klf[0] = ldg_frag(Klb + ko);  klf[1] = ldg_frag(Klb + ko + 32);
        }

        // ---- softmax phase 1: per-wave column maxima ----
        #pragma unroll
        for (int nt = 0; nt < 4; ++nt) {
            float pm = fmaxf(fmaxf(Sacc[nt][0], Sacc[nt][1]),
                             fmaxf(Sacc[nt][2], Sacc[nt][3]));
            pm = fmaxf(pm, __shfl_xor(pm, 16));
            pm = fmaxf(pm, __shfl_xor(pm, 32));
            pmax[w][nt * 16 + lq] = pm;
        }
        __syncthreads();

        // ---- softmax phase 2: new max, exp, P^T, partial sums ----
        float al[4];
        #pragma unroll
        for (int nt = 0; nt < 4; ++nt) {
            int i = nt * 16 + lq;
            float im = fmaxf(fmaxf(pmax[0][i], pmax[1][i]),
                             fmaxf(pmax[2][i], pmax[3][i]));
            float Mn = fmaxf(Mi[nt], im);
            al[nt] = __expf(Mi[nt] - Mn);
            Mi[nt] = Mn;
            float p0 = __expf(Sacc[nt][0] - Mn);
            float p1 = __expf(Sacc[nt][1] - Mn);
            float p2 = __expf(Sacc[nt][2] - Mn);
            float p3 = __expf(Sacc[nt][3] - Mn);
            float ps = (p0 + p1) + (p2 + p3);
            ps += __shfl_xor(ps, 16);
            ps += __shfl_xor(ps, 32);
            psum[w][i] = ps;
            u16x4 pk;
            pk[0] = f2bf(p0); pk[1] = f2bf(p1); pk[2] = f2bf(p2); pk[3] = f2bf(p3);
            *reinterpret_cast<u16x4*>(&PT[i * 72 + w * 16 + quad * 4]) = pk;
        }
        // rescale O accumulator by alpha(n)
        #pragma unroll
        for (int rt = 0; rt < 4; ++rt)
            #pragma unroll
            for (int ct = 0; ct < 4; ++ct)
                Oacc[rt][ct] *= al[ct];
        __syncthreads();

        // running denominator
        #pragma unroll
        for (int nt = 0; nt < 4; ++nt) {
            int i = nt * 16 + lq;
            Li[nt] = Li[nt] * al[nt] +
                     ((psum[0][i] + psum[1][i]) + (psum[2][i] + psum[3][i]));
        }

        // ---- O^T += V^T P^T (this wave's 64 c-rows x 64 n-cols) ----
        #pragma unroll
        for (int ks = 0; ks < 2; ++ks) {
            s16x8 pf[4];
            #pragma unroll
            for (int ct = 0; ct < 4; ++ct)
                pf[ct] = lds_frag(&PT[(ct * 16 + lq) * 72 + ks * 32 + quad * 8]);
            #pragma unroll
            for (int rt = 0; rt < 4; ++rt)
                #pragma unroll
                for (int ct = 0; ct < 4; ++ct)
                    Oacc[rt][ct] = __builtin_amdgcn_mfma_f32_16x16x32_bf16(
                        vf[rt][ks], pf[ct], Oacc[rt][ct], 0, 0, 0);
        }

        // prefetch next V fragments (regs free after MFMA issue)
        #pragma unroll
        for (int rt = 0; rt < 4; ++rt)
            #pragma unroll
            for (int ks = 0; ks < 2; ++ks)
                vf[rt][ks] = ldg_frag(Vb + (size_t)(w * 64 + rt * 16 + lq) * NPIX
                                         + it2 * 64 + ks * 32 + quad * 8);
    }

    // ---- epilogue: out = xq + gamma * O^T / L  (O^T already in [c][n]) ----
    const float* xq = d ? x2 : x1;
    const float gm = gamma[0];
    float inv[4];
    #pragma unroll
    for (int nt = 0; nt < 4; ++nt) inv[nt] = 1.0f / Li[nt];

    #pragma unroll
    for (int rt = 0; rt < 4; ++rt)
        #pragma unroll
        for (int ct = 0; ct < 4; ++ct)
            #pragma unroll
            for (int rg = 0; rg < 4; ++rg) {
                int c = w * 64 + rt * 16 + quad * 4 + rg;
                int nn = n0 + ct * 16 + lq;
                size_t src = (size_t)(b * CCH + c) * NPIX + nn;
                size_t dst = (size_t)((d * BAT + b) * CCH + c) * NPIX + nn;
                out[dst] = xq[src] + gm * Oacc[rt][ct][rg] * inv[ct];
            }
}

// ---------------------------------------------------------------------------
extern "C" void kernel_launch(void* const* d_in, const int* in_sizes, int n_in,
                              void* d_out, int out_size, void* d_ws, size_t ws_size,
                              hipStream_t stream) {
    (void)in_sizes; (void)n_in; (void)out_size; (void)ws_size;
    const float* x1 = (const float*)d_in[0];
    const float* x2 = (const float*)d_in[1];
    const float* Wq = (const float*)d_in[2];
    const float* bq = (const float*)d_in[3];
    const float* Wk = (const float*)d_in[4];
    const float* bk = (const float*)d_in[5];
    const float* Wv = (const float*)d_in[6];
    const float* bv = (const float*)d_in[7];
    const float* gm = (const float*)d_in[8];
    float* out = (float*)d_out;

    // workspace layout (32 MB total): Qh|Ql|Kh|Kl (4 MB each) + Vt (16 MB)
    unsigned short* ws = (unsigned short*)d_ws;
    const size_t QKELEM = (size_t)2 * BAT * NPIX * HID;   // 2,097,152
    unsigned short* Qh = ws;
    unsigned short* Ql = Qh + QKELEM;
    unsigned short* Kh = Ql + QKELEM;
    unsigned short* Kl = Kh + QKELEM;
    unsigned short* Vt = Kl + QKELEM;                     // 8,388,608 elems

    proj_kernel<<<dim3(512), dim3(256), 0, stream>>>(
        x1, x2, Wq, bq, Wk, bk, Wv, bv, Qh, Ql, Kh, Kl, Vt);
    attn_kernel<<<dim3(512), dim3(256), 0, stream>>>(
        x1, x2, Qh, Ql, Kh, Kl, Vt, gm, out);
}

// Round 2
// 336.735 us; speedup vs baseline: 1.6763x; 1.6763x over previous
//
#include <hip/hip_runtime.h>
#include <hip/hip_bf16.h>

#define NPIX 4096
#define CCH  256
#define HID  64
#define BAT  4
#define XSTR 264   // LDS row stride (elems): b128 reads min-rate, b64 writes conflict-free

using f32x4 = __attribute__((ext_vector_type(4))) float;
using s16x8 = __attribute__((ext_vector_type(8))) short;
using u16x4 = __attribute__((ext_vector_type(4))) unsigned short;

__device__ __forceinline__ unsigned short f2bf(float f) {
    __hip_bfloat16 h = __float2bfloat16(f);
    return __builtin_bit_cast(unsigned short, h);
}
__device__ __forceinline__ float bf2f(unsigned short u) {
    unsigned int v = ((unsigned int)u) << 16;
    return __builtin_bit_cast(float, v);
}
__device__ __forceinline__ s16x8 ldg_frag(const unsigned short* p) {
    uint4 v = *reinterpret_cast<const uint4*>(p);
    return __builtin_bit_cast(s16x8, v);
}
__device__ __forceinline__ s16x8 lds_frag(const unsigned short* p) {
    return *reinterpret_cast<const s16x8*>(p);
}

// ---------------------------------------------------------------------------
// W conversion: Wq(64x256), Wk(64x256), Wv(256x256) fp32 -> concatenated
// row-major [384][256] bf16 hi + lo. Rows 0-63 q, 64-127 k, 128-383 v.
// ---------------------------------------------------------------------------
__global__ __launch_bounds__(256, 1) void wcvt_kernel(
    const float* __restrict__ Wq, const float* __restrict__ Wk,
    const float* __restrict__ Wv,
    unsigned short* __restrict__ Wh, unsigned short* __restrict__ Wl)
{
    int idx = (blockIdx.x * 256 + threadIdx.x) * 4;   // 384*256 = 98304 elems
    int r = idx >> 8, c = idx & 255;
    const float* src = (r < 64)  ? (Wq + r * CCH + c)
                     : (r < 128) ? (Wk + (r - 64) * CCH + c)
                                 : (Wv + (r - 128) * CCH + c);
    float4 v4 = *reinterpret_cast<const float4*>(src);
    float vv[4] = {v4.x, v4.y, v4.z, v4.w};
    u16x4 hv, lv;
    #pragma unroll
    for (int j = 0; j < 4; ++j) {
        unsigned short hb = f2bf(vv[j]);
        hv[j] = hb;
        lv[j] = f2bf(vv[j] - bf2f(hb));
    }
    *reinterpret_cast<u16x4*>(Wh + idx) = hv;
    *reinterpret_cast<u16x4*>(Wl + idx) = lv;
}

// ---------------------------------------------------------------------------
// MFMA projection. Block = (s, b, 32-pixel tile). Stages x^T hi/lo bf16 in
// LDS. Split-bf16 (3-MFMA) products keep fp32-level accuracy in q/k/v.
//  - V rows:  D[c][n] = mfma(Wfrag, xfrag) -> store Vt [c][n] directly
//  - Q/K rows: D[n][h] = mfma(xfrag, Wfrag) -> split hi/lo, store [n][h]
// Both orientations use the same 16B-contiguous fragment loads.
// 24 htiles (4 Q, 4 K, 16 V) x 2 ntiles per block; wave owns 6 htiles
// processed as 3 pairs (W-frags for a pair resident in 128 VGPRs).
// ---------------------------------------------------------------------------
__global__ __launch_bounds__(256, 2) void proj_kernel(
    const float* __restrict__ x1, const float* __restrict__ x2,
    const unsigned short* __restrict__ Wh, const unsigned short* __restrict__ Wl,
    const float* __restrict__ bq, const float* __restrict__ bk,
    const float* __restrict__ bv,
    unsigned short* __restrict__ Qh, unsigned short* __restrict__ Ql,
    unsigned short* __restrict__ Kh, unsigned short* __restrict__ Kl,
    unsigned short* __restrict__ Vt)
{
    __shared__ unsigned short xs_h[32][XSTR];
    __shared__ unsigned short xs_l[32][XSTR];

    const int Lb = blockIdx.x;
    const int sb = Lb & 7;              // XCD-locality swizzle
    const int tile = Lb >> 3;
    const int s = sb >> 2, b = sb & 3;
    const float* x = s ? x2 : x1;
    const int n0 = tile * 32;
    const int t = threadIdx.x;
    const int lane = t & 63;
    const int w = __builtin_amdgcn_readfirstlane(t >> 6);
    const int quad = lane >> 4, lq = lane & 15;

    // ---- stage x^T hi/lo into LDS (transpose via per-thread 4-c packing) ----
    {
        const int n = t & 31;
        const int g = t >> 5;           // 0..7
        const float* xb = x + (size_t)(b * CCH) * NPIX + n0;
        #pragma unroll
        for (int i = 0; i < 8; ++i) {
            int c0 = g * 4 + i * 32;
            u16x4 hv, lv;
            #pragma unroll
            for (int j = 0; j < 4; ++j) {
                float v = xb[(size_t)(c0 + j) * NPIX + n];
                unsigned short hb = f2bf(v);
                hv[j] = hb;
                lv[j] = f2bf(v - bf2f(hb));
            }
            *reinterpret_cast<u16x4*>(&xs_h[n][c0]) = hv;
            *reinterpret_cast<u16x4*>(&xs_l[n][c0]) = lv;
        }
    }
    __syncthreads();

    const int sbN = (s * BAT + b) * NPIX;
    const int sbC = (s * BAT + b) * CCH;

    for (int p = 0; p < 3; ++p) {
        const int idx0 = w * 6 + p * 2;                 // wave-uniform
        const int kind = idx0 < 4 ? 0 : (idx0 < 8 ? 1 : 2);

        // load W fragments for this pair of htiles (rows idx*16 + lq)
        s16x8 wfh[2][8], wfl[2][8];
        #pragma unroll
        for (int h = 0; h < 2; ++h) {
            const unsigned short* wph = Wh + (size_t)((idx0 + h) * 16 + lq) * CCH + quad * 8;
            const unsigned short* wpl = Wl + (size_t)((idx0 + h) * 16 + lq) * CCH + quad * 8;
            #pragma unroll
            for (int ks = 0; ks < 8; ++ks) {
                wfh[h][ks] = ldg_frag(wph + ks * 32);
                wfl[h][ks] = ldg_frag(wpl + ks * 32);
            }
        }

        #pragma unroll
        for (int ntile = 0; ntile < 2; ++ntile) {
            f32x4 acc[2];
            acc[0] = (f32x4){0.f, 0.f, 0.f, 0.f};
            acc[1] = (f32x4){0.f, 0.f, 0.f, 0.f};
            const unsigned short* xrh = &xs_h[ntile * 16 + lq][quad * 8];
            const unsigned short* xrl = &xs_l[ntile * 16 + lq][quad * 8];

            if (kind == 2) {
                #pragma unroll
                for (int ks = 0; ks < 8; ++ks) {
                    s16x8 xh = lds_frag(xrh + ks * 32);
                    s16x8 xl = lds_frag(xrl + ks * 32);
                    #pragma unroll
                    for (int h = 0; h < 2; ++h) {
                        acc[h] = __builtin_amdgcn_mfma_f32_16x16x32_bf16(wfh[h][ks], xh, acc[h], 0, 0, 0);
                        acc[h] = __builtin_amdgcn_mfma_f32_16x16x32_bf16(wfl[h][ks], xh, acc[h], 0, 0, 0);
                        acc[h] = __builtin_amdgcn_mfma_f32_16x16x32_bf16(wfh[h][ks], xl, acc[h], 0, 0, 0);
                    }
                }
                // V epilogue: D[c][n], c = (idx-8)*16 + quad*4 + reg, n = lq
                #pragma unroll
                for (int h = 0; h < 2; ++h) {
                    int cbase = (idx0 + h - 8) * 16 + quad * 4;
                    int nn = n0 + ntile * 16 + lq;
                    #pragma unroll
                    for (int reg = 0; reg < 4; ++reg) {
                        int c = cbase + reg;
                        float v = acc[h][reg] + bv[c];
                        Vt[(size_t)(sbC + c) * NPIX + nn] = f2bf(v);
                    }
                }
            } else {
                #pragma unroll
                for (int ks = 0; ks < 8; ++ks) {
                    s16x8 xh = lds_frag(xrh + ks * 32);
                    s16x8 xl = lds_frag(xrl + ks * 32);
                    #pragma unroll
                    for (int h = 0; h < 2; ++h) {
                        acc[h] = __builtin_amdgcn_mfma_f32_16x16x32_bf16(xh, wfh[h][ks], acc[h], 0, 0, 0);
                        acc[h] = __builtin_amdgcn_mfma_f32_16x16x32_bf16(xh, wfl[h][ks], acc[h], 0, 0, 0);
                        acc[h] = __builtin_amdgcn_mfma_f32_16x16x32_bf16(xl, wfh[h][ks], acc[h], 0, 0, 0);
                    }
                }
                // Q/K epilogue: D[n][h], n = quad*4 + reg, h = local*16 + lq
                unsigned short* dh = (kind ? Kh : Qh);
                unsigned short* dl = (kind ? Kl : Ql);
                const float* bias = (kind ? bk : bq);
                #pragma unroll
                for (int h = 0; h < 2; ++h) {
                    int hl = (kind ? (idx0 + h - 4) : (idx0 + h)) * 16 + lq;
                    float bb = bias[hl];
                    #pragma unroll
                    for (int reg = 0; reg < 4; ++reg) {
                        int nn = n0 + ntile * 16 + quad * 4 + reg;
                        float v = acc[h][reg] + bb;
                        unsigned short hb = f2bf(v);
                        float res = v - bf2f(hb);
                        dh[(size_t)(sbN + nn) * HID + hl] = hb;
                        dl[(size_t)(sbN + nn) * HID + hl] = f2bf(res);
                    }
                }
            }
        }
    }
}

// ---------------------------------------------------------------------------
// Flash cross-attention, transposed orientation (unchanged from round 1):
//   S^T = K Q^T (split-bf16, 3 MFMA), online softmax over m, O^T = V^T P^T.
// ---------------------------------------------------------------------------
__global__ __launch_bounds__(256, 2) void attn_kernel(
    const float* __restrict__ x1, const float* __restrict__ x2,
    const unsigned short* __restrict__ Qh, const unsigned short* __restrict__ Ql,
    const unsigned short* __restrict__ Kh, const unsigned short* __restrict__ Kl,
    const unsigned short* __restrict__ Vt,
    const float* __restrict__ gamma,
    float* __restrict__ out)
{
    __shared__ unsigned short PT[64 * 72];   // P^T [n][m], +8 pad
    __shared__ float pmax[4][64];
    __shared__ float psum[4][64];

    const int Lb = blockIdx.x;
    const int g = Lb & 7;                    // XCD-locality swizzle
    const int ntile = Lb >> 3;
    const int d = g >> 2, b = g & 3;
    const int s = d, r = 1 - d;
    const int n0 = ntile * 64;

    const int t = threadIdx.x;
    const int lane = t & 63;
    const int w = __builtin_amdgcn_readfirstlane(t >> 6);
    const int quad = lane >> 4, lq = lane & 15;

    const unsigned short* Qhb = Qh + (size_t)(s * BAT + b) * NPIX * HID;
    const unsigned short* Qlb = Ql + (size_t)(s * BAT + b) * NPIX * HID;
    const unsigned short* Khb = Kh + (size_t)(r * BAT + b) * NPIX * HID;
    const unsigned short* Klb = Kl + (size_t)(r * BAT + b) * NPIX * HID;
    const unsigned short* Vb  = Vt + (size_t)(r * BAT + b) * CCH * NPIX;

    s16x8 qhf[4][2], qlf[4][2];
    #pragma unroll
    for (int nt = 0; nt < 4; ++nt)
        #pragma unroll
        for (int ks = 0; ks < 2; ++ks) {
            int off = (n0 + nt * 16 + lq) * HID + ks * 32 + quad * 8;
            qhf[nt][ks] = ldg_frag(Qhb + off);
            qlf[nt][ks] = ldg_frag(Qlb + off);
        }

    f32x4 Oacc[4][4];
    #pragma unroll
    for (int rt = 0; rt < 4; ++rt)
        #pragma unroll
        for (int ct = 0; ct < 4; ++ct)
            Oacc[rt][ct] = (f32x4){0.f, 0.f, 0.f, 0.f};

    float Mi[4], Li[4];
    #pragma unroll
    for (int nt = 0; nt < 4; ++nt) { Mi[nt] = -3.0e38f; Li[nt] = 0.f; }

    s16x8 khf[2], klf[2], vf[4][2];
    {
        int ko = (w * 16 + lq) * HID + quad * 8;
        khf[0] = ldg_frag(Khb + ko);      khf[1] = ldg_frag(Khb + ko + 32);
        klf[0] = ldg_frag(Klb + ko);      klf[1] = ldg_frag(Klb + ko + 32);
        #pragma unroll
        for (int rt = 0; rt < 4; ++rt)
            #pragma unroll
            for (int ks = 0; ks < 2; ++ks)
                vf[rt][ks] = ldg_frag(Vb + (size_t)(w * 64 + rt * 16 + lq) * NPIX
                                         + ks * 32 + quad * 8);
    }

    for (int it = 0; it < 64; ++it) {
        f32x4 Sacc[4];
        #pragma unroll
        for (int nt = 0; nt < 4; ++nt) Sacc[nt] = (f32x4){0.f, 0.f, 0.f, 0.f};
        #pragma unroll
        for (int ks = 0; ks < 2; ++ks)
            #pragma unroll
            for (int nt = 0; nt < 4; ++nt) {
                Sacc[nt] = __builtin_amdgcn_mfma_f32_16x16x32_bf16(khf[ks], qhf[nt][ks], Sacc[nt], 0, 0, 0);
                Sacc[nt] = __builtin_amdgcn_mfma_f32_16x16x32_bf16(khf[ks], qlf[nt][ks], Sacc[nt], 0, 0, 0);
                Sacc[nt] = __builtin_amdgcn_mfma_f32_16x16x32_bf16(klf[ks], qhf[nt][ks], Sacc[nt], 0, 0, 0);
            }

        const int it2 = (it < 63) ? it + 1 : 63;
        {
            int ko = (it2 * 64 + w * 16 + lq) * HID + quad * 8;
            khf[0] = ldg_frag(Khb + ko);  khf[1] = ldg_frag(Khb + ko + 32);
            klf[0] = ldg_frag(Klb + ko);  klf[1] = ldg_frag(Klb + ko + 32);
        }

        #pragma unroll
        for (int nt = 0; nt < 4; ++nt) {
            float pm = fmaxf(fmaxf(Sacc[nt][0], Sacc[nt][1]),
                             fmaxf(Sacc[nt][2], Sacc[nt][3]));
            pm = fmaxf(pm, __shfl_xor(pm, 16));
            pm = fmaxf(pm, __shfl_xor(pm, 32));
            pmax[w][nt * 16 + lq] = pm;
        }
        __syncthreads();

        float al[4];
        #pragma unroll
        for (int nt = 0; nt < 4; ++nt) {
            int i = nt * 16 + lq;
            float im = fmaxf(fmaxf(pmax[0][i], pmax[1][i]),
                             fmaxf(pmax[2][i], pmax[3][i]));
            float Mn = fmaxf(Mi[nt], im);
            al[nt] = __expf(Mi[nt] - Mn);
            Mi[nt] = Mn;
            float p0 = __expf(Sacc[nt][0] - Mn);
            float p1 = __expf(Sacc[nt][1] - Mn);
            float p2 = __expf(Sacc[nt][2] - Mn);
            float p3 = __expf(Sacc[nt][3] - Mn);
            float ps = (p0 + p1) + (p2 + p3);
            ps += __shfl_xor(ps, 16);
            ps += __shfl_xor(ps, 32);
            psum[w][i] = ps;
            u16x4 pk;
            pk[0] = f2bf(p0); pk[1] = f2bf(p1); pk[2] = f2bf(p2); pk[3] = f2bf(p3);
            *reinterpret_cast<u16x4*>(&PT[i * 72 + w * 16 + quad * 4]) = pk;
        }
        #pragma unroll
        for (int rt = 0; rt < 4; ++rt)
            #pragma unroll
            for (int ct = 0; ct < 4; ++ct)
                Oacc[rt][ct] *= al[ct];
        __syncthreads();

        #pragma unroll
        for (int nt = 0; nt < 4; ++nt) {
            int i = nt * 16 + lq;
            Li[nt] = Li[nt] * al[nt] +
                     ((psum[0][i] + psum[1][i]) + (psum[2][i] + psum[3][i]));
        }

        #pragma unroll
        for (int ks = 0; ks < 2; ++ks) {
            s16x8 pf[4];
            #pragma unroll
            for (int ct = 0; ct < 4; ++ct)
                pf[ct] = lds_frag(&PT[(ct * 16 + lq) * 72 + ks * 32 + quad * 8]);
            #pragma unroll
            for (int rt = 0; rt < 4; ++rt)
                #pragma unroll
                for (int ct = 0; ct < 4; ++ct)
                    Oacc[rt][ct] = __builtin_amdgcn_mfma_f32_16x16x32_bf16(
                        vf[rt][ks], pf[ct], Oacc[rt][ct], 0, 0, 0);
        }

        #pragma unroll
        for (int rt = 0; rt < 4; ++rt)
            #pragma unroll
            for (int ks = 0; ks < 2; ++ks)
                vf[rt][ks] = ldg_frag(Vb + (size_t)(w * 64 + rt * 16 + lq) * NPIX
                                         + it2 * 64 + ks * 32 + quad * 8);
    }

    const float* xq = d ? x2 : x1;
    const float gm = gamma[0];
    float inv[4];
    #pragma unroll
    for (int nt = 0; nt < 4; ++nt) inv[nt] = 1.0f / Li[nt];

    #pragma unroll
    for (int rt = 0; rt < 4; ++rt)
        #pragma unroll
        for (int ct = 0; ct < 4; ++ct)
            #pragma unroll
            for (int rg = 0; rg < 4; ++rg) {
                int c = w * 64 + rt * 16 + quad * 4 + rg;
                int nn = n0 + ct * 16 + lq;
                size_t src = (size_t)(b * CCH + c) * NPIX + nn;
                size_t dst = (size_t)((d * BAT + b) * CCH + c) * NPIX + nn;
                out[dst] = xq[src] + gm * Oacc[rt][ct][rg] * inv[ct];
            }
}

// ---------------------------------------------------------------------------
extern "C" void kernel_launch(void* const* d_in, const int* in_sizes, int n_in,
                              void* d_out, int out_size, void* d_ws, size_t ws_size,
                              hipStream_t stream) {
    (void)in_sizes; (void)n_in; (void)out_size; (void)ws_size;
    const float* x1 = (const float*)d_in[0];
    const float* x2 = (const float*)d_in[1];
    const float* Wq = (const float*)d_in[2];
    const float* bq = (const float*)d_in[3];
    const float* Wk = (const float*)d_in[4];
    const float* bk = (const float*)d_in[5];
    const float* Wv = (const float*)d_in[6];
    const float* bv = (const float*)d_in[7];
    const float* gm = (const float*)d_in[8];
    float* out = (float*)d_out;

    // workspace: Qh|Ql|Kh|Kl (4 MB each) + Vt (16 MB) + Whc/Wlc (0.2 MB each)
    unsigned short* ws = (unsigned short*)d_ws;
    const size_t QKELEM = (size_t)2 * BAT * NPIX * HID;   // 2,097,152
    unsigned short* Qh = ws;
    unsigned short* Ql = Qh + QKELEM;
    unsigned short* Kh = Ql + QKELEM;
    unsigned short* Kl = Kh + QKELEM;
    unsigned short* Vt = Kl + QKELEM;                     // 8,388,608 elems
    unsigned short* Whc = Vt + (size_t)2 * BAT * CCH * NPIX;
    unsigned short* Wlc = Whc + 384 * CCH;

    wcvt_kernel<<<dim3(96), dim3(256), 0, stream>>>(Wq, Wk, Wv, Whc, Wlc);
    proj_kernel<<<dim3(1024), dim3(256), 0, stream>>>(
        x1, x2, Whc, Wlc, bq, bk, bv, Qh, Ql, Kh, Kl, Vt);
    attn_kernel<<<dim3(512), dim3(256), 0, stream>>>(
        x1, x2, Qh, Ql, Kh, Kl, Vt, gm, out);
}